// Round 1
// baseline (383.740 us; speedup 1.0000x reference)
//
#include <hip/hip_runtime.h>

// NCC loss: five 9x9x9 box sums over (2,1,160,160,160) fp32 volumes, fused.
// Separable box filter; block owns a 16x16 (h,w) tile, streams 16 outputs
// along D. D-direction 9-tap window kept in REGISTERS (ring[9][5], slot index
// made compile-time by outer-3 x inner-unrolled-9 loop structure).
//
// R1 changes vs baseline (theory: latency-bound, grid-limited occupancy):
//  - SINGLE-buffered LDS: with the A|sync|B|sync|C structure, A(k+1) writes
//    are ordered after B(k) reads by sync2(k), and B(k+1) writes after C(k)
//    reads by sync1(k+1) -> the double buffer was dead weight. 25.1->12.5 KB.
//  - DCHUNK 32->16: grid 1000 -> 2000 blocks (8000 waves ~ 98% of the 8192
//    device wave slots, all co-resident). +20% staging redundancy accepted.
//  - __launch_bounds__(256, 8): 8 blocks/CU (VGPR cap 64; was 60 used).
//  - finalize fused into the last-finishing block (atomic counter), the
//    separate 1-thread kernel launch is gone.
// d_ws: [0:8) double accumulator, [8:12) unsigned completion counter.

#define NB   2
#define NDIM 160
#define TILE 16
#define RE   24      // TILE + 8 halo
#define DCHUNK 16
#define NDCHUNK (NDIM / DCHUNK)   // 10
#define NSLICE (DCHUNK + 8)       // 24 real slices per block
#define NBLK ((NDIM/TILE)*(NDIM/TILE)*NB*NDCHUNK)   // 2000

__global__ __launch_bounds__(256, 8)
void ncc_main(const float* __restrict__ I, const float* __restrict__ J,
              double* __restrict__ out_acc, unsigned int* __restrict__ out_cnt,
              float* __restrict__ out) {
    const int t  = threadIdx.x;
    const int tx = t & 15;
    const int ty = t >> 4;
    const int w0 = blockIdx.x * TILE;
    const int h0 = blockIdx.y * TILE;
    const int b  = blockIdx.z / NDCHUNK;
    const int d0 = (blockIdx.z % NDCHUNK) * DCHUNK;

    const float* Ib = I + (size_t)b * NDIM * NDIM * NDIM;
    const float* Jb = J + (size_t)b * NDIM * NDIM * NDIM;

    // Single-buffered LDS (safe with the 2 barriers below; see header note).
    __shared__ float2 sIJ[RE][25];       // interleaved I,J halo (col pad)
    __shared__ float4 rsv[RE][TILE];     // row sums: {I, J, I2, J2}
    __shared__ float  rss[RE][TILE];     // row sums: IJ
    __shared__ double wsum[4];

    // D-window ring in REGISTERS: ring[j][c], j indexed by constants only.
    float ring[9][5];
#pragma unroll
    for (int k = 0; k < 9; ++k)
#pragma unroll
        for (int c = 0; c < 5; ++c) ring[k][c] = 0.0f;

    float acc[5] = {0.f, 0.f, 0.f, 0.f, 0.f};
    double csum = 0.0;
    const float inv_win = 1.0f / 729.0f;

    // 27 steps (24 real + 3 dummy so step%9 == j is exact); slice dz = d0-4+step.
    // After folding slice dz, acc = box-sum over slices [dz-8, dz]; output
    // d = dz-4 is emitted for steps 8..23.
    for (int o = 0; o < 3; ++o) {
#pragma unroll
        for (int j = 0; j < 9; ++j) {
            const int step = o * 9 + j;
            const int dz = d0 - 4 + step;
            float s[5] = {0.f, 0.f, 0.f, 0.f, 0.f};
            if (step < NSLICE && (unsigned)dz < NDIM) {   // block-uniform
                // Phase A: stage 24x24 halo (zero-padded) as float2
                for (int e = t; e < RE * RE; e += 256) {
                    int r = e / RE, c2 = e - r * RE;
                    int h = h0 - 4 + r, w = w0 - 4 + c2;
                    float vi = 0.f, vj = 0.f;
                    if ((unsigned)h < NDIM && (unsigned)w < NDIM) {
                        size_t idx = ((size_t)dz * NDIM + h) * NDIM + w;
                        vi = Ib[idx];
                        vj = Jb[idx];
                    }
                    sIJ[r][c2] = make_float2(vi, vj);
                }
                __syncthreads();
                // Phase B: 9-tap row sums along W, 5 channels, 24x16 items
                for (int p = t; p < RE * TILE; p += 256) {
                    int r = p >> 4, wo = p & 15;
                    float a0 = 0.f, a1 = 0.f, a2 = 0.f, a3 = 0.f, a4 = 0.f;
#pragma unroll
                    for (int k = 0; k < 9; ++k) {
                        float2 v = sIJ[r][wo + k];
                        a0 += v.x; a1 += v.y;
                        a2 += v.x * v.x; a3 += v.y * v.y; a4 += v.x * v.y;
                    }
                    rsv[r][wo] = make_float4(a0, a1, a2, a3);
                    rss[r][wo] = a4;
                }
                __syncthreads();
                // Phase C: 9-tap column sums along H at (ty, tx)
                float s0 = 0.f, s1 = 0.f, s2 = 0.f, s3 = 0.f, s4 = 0.f;
#pragma unroll
                for (int k = 0; k < 9; ++k) {
                    float4 v = rsv[ty + k][tx];
                    s0 += v.x; s1 += v.y; s2 += v.z; s3 += v.w;
                    s4 += rss[ty + k][tx];
                }
                s[0] = s0; s[1] = s1; s[2] = s2; s[3] = s3; s[4] = s4;
            }
            // Slide the D-window (constant slot j -> pure registers)
#pragma unroll
            for (int c = 0; c < 5; ++c) {
                acc[c] += s[c] - ring[j][c];
                ring[j][c] = s[c];
            }
            if (step >= 8 && step < 8 + DCHUNK) {
                float Is = acc[0], Js = acc[1];
                float I2 = acc[2], J2 = acc[3], IJ = acc[4];
                float cross = IJ - Is * Js * inv_win;
                float Ivar  = I2 - Is * Is * inv_win;
                float Jvar  = J2 - Js * Js * inv_win;
                float cc = cross * cross / (Ivar * Jvar + 1e-5f);
                csum += (double)cc;
            }
        }
    }

    // Block reduction: wave shuffle, then cross-wave via LDS.
#pragma unroll
    for (int off = 32; off > 0; off >>= 1)
        csum += __shfl_down(csum, off, 64);
    if ((t & 63) == 0) wsum[t >> 6] = csum;
    __syncthreads();
    if (t == 0) {
        double total = wsum[0] + wsum[1] + wsum[2] + wsum[3];
        atomicAdd(out_acc, total);
        __threadfence();
        unsigned int old = atomicAdd(out_cnt, 1u);
        if (old == NBLK - 1) {
            // All other blocks' acc adds are ordered before their counter
            // increments (threadfence); atomic read returns the full total.
            double fin = atomicAdd(out_acc, 0.0);
            out[0] = (float)(-fin / 8192000.0);
        }
    }
}

extern "C" void kernel_launch(void* const* d_in, const int* in_sizes, int n_in,
                              void* d_out, int out_size, void* d_ws, size_t ws_size,
                              hipStream_t stream) {
    const float* I = (const float*)d_in[0];   // y_true
    const float* J = (const float*)d_in[1];   // y_pred
    double* acc = (double*)d_ws;
    unsigned int* cnt = (unsigned int*)((char*)d_ws + 8);

    hipMemsetAsync(d_ws, 0, 16, stream);

    dim3 grid(NDIM / TILE, NDIM / TILE, NB * NDCHUNK);  // 10 x 10 x 20
    ncc_main<<<grid, 256, 0, stream>>>(I, J, acc, cnt, (float*)d_out);
}

// Round 3
// 360.636 us; speedup vs baseline: 1.0641x; 1.0641x over previous
//
#include <hip/hip_runtime.h>

// NCC loss: five 9x9x9 box sums over (2,1,160,160,160) fp32 volumes, fused.
// Separable box filter; block owns a 16x16 (h,w) tile, streams 20 outputs
// along D. D-direction 9-tap window kept in REGISTERS (ring[9][5], slot index
// made compile-time by outer-4 x inner-unrolled-9 loop structure).
//
// R3 == R2 resubmitted (R2 bench died on container infra, no measurement).
// R2 rationale vs R1 (post-mortem: launch_bounds(256,8) capped VGPR at 64 ->
// allocator spilled the ring buffer to scratch: VGPR 60->32, WRITE_SIZE
// 31KB->464MB, VALUBusy 19%, 3x slower):
//  - __launch_bounds__(256, 6): VGPR cap 84 >= the ~60 this kernel needs.
//    6 blocks/CU = 24 waves/CU (75% occupancy ceiling), NO spill.
//  - DCHUNK 20: grid = 10x10x16 = 1600 blocks ~= 256 CU x 6 slots, full
//    co-residency with a small tail; halo redundancy 28/20 = 1.4.
//  - keeps R1's single-buffered LDS (12.8 KB) + fused finalize.
// d_ws: [0:8) double accumulator, [8:12) unsigned completion counter.

#define NB   2
#define NDIM 160
#define TILE 16
#define RE   24      // TILE + 8 halo
#define DCHUNK 20
#define NDCHUNK (NDIM / DCHUNK)   // 8
#define NSLICE (DCHUNK + 8)       // 28 real slices per block
#define NBLK ((NDIM/TILE)*(NDIM/TILE)*NB*NDCHUNK)   // 1600

__global__ __launch_bounds__(256, 6)
void ncc_main(const float* __restrict__ I, const float* __restrict__ J,
              double* __restrict__ out_acc, unsigned int* __restrict__ out_cnt,
              float* __restrict__ out) {
    const int t  = threadIdx.x;
    const int tx = t & 15;
    const int ty = t >> 4;
    const int w0 = blockIdx.x * TILE;
    const int h0 = blockIdx.y * TILE;
    const int b  = blockIdx.z / NDCHUNK;
    const int d0 = (blockIdx.z % NDCHUNK) * DCHUNK;

    const float* Ib = I + (size_t)b * NDIM * NDIM * NDIM;
    const float* Jb = J + (size_t)b * NDIM * NDIM * NDIM;

    // Single-buffered LDS: A(k+1) writes are ordered after B(k) reads by
    // sync2(k); B(k+1) writes after C(k) reads by sync1(k+1).
    __shared__ float2 sIJ[RE][25];       // interleaved I,J halo (col pad)
    __shared__ float4 rsv[RE][TILE];     // row sums: {I, J, I2, J2}
    __shared__ float  rss[RE][TILE];     // row sums: IJ
    __shared__ double wsum[4];

    // D-window ring in REGISTERS: ring[j][c], j indexed by constants only.
    float ring[9][5];
#pragma unroll
    for (int k = 0; k < 9; ++k)
#pragma unroll
        for (int c = 0; c < 5; ++c) ring[k][c] = 0.0f;

    float acc[5] = {0.f, 0.f, 0.f, 0.f, 0.f};
    double csum = 0.0;
    const float inv_win = 1.0f / 729.0f;

    // 36 steps (28 real + 8 dummy so step%9 == j is exact); slice dz = d0-4+step.
    // After folding slice dz, acc = box-sum over slices [dz-8, dz]; output
    // d = dz-4 is emitted for steps 8..27.
    for (int o = 0; o < 4; ++o) {
#pragma unroll
        for (int j = 0; j < 9; ++j) {
            const int step = o * 9 + j;
            const int dz = d0 - 4 + step;
            float s[5] = {0.f, 0.f, 0.f, 0.f, 0.f};
            if (step < NSLICE && (unsigned)dz < NDIM) {   // block-uniform
                // Phase A: stage 24x24 halo (zero-padded) as float2
                for (int e = t; e < RE * RE; e += 256) {
                    int r = e / RE, c2 = e - r * RE;
                    int h = h0 - 4 + r, w = w0 - 4 + c2;
                    float vi = 0.f, vj = 0.f;
                    if ((unsigned)h < NDIM && (unsigned)w < NDIM) {
                        size_t idx = ((size_t)dz * NDIM + h) * NDIM + w;
                        vi = Ib[idx];
                        vj = Jb[idx];
                    }
                    sIJ[r][c2] = make_float2(vi, vj);
                }
                __syncthreads();
                // Phase B: 9-tap row sums along W, 5 channels, 24x16 items
                for (int p = t; p < RE * TILE; p += 256) {
                    int r = p >> 4, wo = p & 15;
                    float a0 = 0.f, a1 = 0.f, a2 = 0.f, a3 = 0.f, a4 = 0.f;
#pragma unroll
                    for (int k = 0; k < 9; ++k) {
                        float2 v = sIJ[r][wo + k];
                        a0 += v.x; a1 += v.y;
                        a2 += v.x * v.x; a3 += v.y * v.y; a4 += v.x * v.y;
                    }
                    rsv[r][wo] = make_float4(a0, a1, a2, a3);
                    rss[r][wo] = a4;
                }
                __syncthreads();
                // Phase C: 9-tap column sums along H at (ty, tx)
                float s0 = 0.f, s1 = 0.f, s2 = 0.f, s3 = 0.f, s4 = 0.f;
#pragma unroll
                for (int k = 0; k < 9; ++k) {
                    float4 v = rsv[ty + k][tx];
                    s0 += v.x; s1 += v.y; s2 += v.z; s3 += v.w;
                    s4 += rss[ty + k][tx];
                }
                s[0] = s0; s[1] = s1; s[2] = s2; s[3] = s3; s[4] = s4;
            }
            // Slide the D-window (constant slot j -> pure registers)
#pragma unroll
            for (int c = 0; c < 5; ++c) {
                acc[c] += s[c] - ring[j][c];
                ring[j][c] = s[c];
            }
            if (step >= 8 && step < 8 + DCHUNK) {
                float Is = acc[0], Js = acc[1];
                float I2 = acc[2], J2 = acc[3], IJ = acc[4];
                float cross = IJ - Is * Js * inv_win;
                float Ivar  = I2 - Is * Is * inv_win;
                float Jvar  = J2 - Js * Js * inv_win;
                float cc = cross * cross / (Ivar * Jvar + 1e-5f);
                csum += (double)cc;
            }
        }
    }

    // Block reduction: wave shuffle, then cross-wave via LDS.
#pragma unroll
    for (int off = 32; off > 0; off >>= 1)
        csum += __shfl_down(csum, off, 64);
    if ((t & 63) == 0) wsum[t >> 6] = csum;
    __syncthreads();
    if (t == 0) {
        double total = wsum[0] + wsum[1] + wsum[2] + wsum[3];
        atomicAdd(out_acc, total);
        __threadfence();
        unsigned int old = atomicAdd(out_cnt, 1u);
        if (old == NBLK - 1) {
            // All other blocks' acc adds are ordered before their counter
            // increments (threadfence); atomic read returns the full total.
            double fin = atomicAdd(out_acc, 0.0);
            out[0] = (float)(-fin / 8192000.0);
        }
    }
}

extern "C" void kernel_launch(void* const* d_in, const int* in_sizes, int n_in,
                              void* d_out, int out_size, void* d_ws, size_t ws_size,
                              hipStream_t stream) {
    const float* I = (const float*)d_in[0];   // y_true
    const float* J = (const float*)d_in[1];   // y_pred
    double* acc = (double*)d_ws;
    unsigned int* cnt = (unsigned int*)((char*)d_ws + 8);

    hipMemsetAsync(d_ws, 0, 16, stream);

    dim3 grid(NDIM / TILE, NDIM / TILE, NB * NDCHUNK);  // 10 x 10 x 16
    ncc_main<<<grid, 256, 0, stream>>>(I, J, acc, cnt, (float*)d_out);
}

// Round 4
// 233.733 us; speedup vs baseline: 1.6418x; 1.5429x over previous
//
#include <hip/hip_runtime.h>

// NCC loss: five 9x9x9 box sums over (2,1,160,160,160) fp32 volumes, fused.
// Separable box filter; block owns a 16x16 (h,w) tile, streams 16 outputs
// along D. D-direction 9-tap window kept in REGISTERS (ring[9][5], slot index
// made compile-time by outer-3 x inner-unrolled-9 loop structure).
//
// R4 post-mortem lineage:
//  - R1 (256,8) and R3 (256,6): the allocator split the register budget and
//    allocated exactly HALF the nominal cap (32 and 40 VGPR), scratch-spilling
//    the ring buffer: WRITE_SIZE 464/337 MB, VALUBusy 19%. Launch-bounds
//    waves-arg >= 6 poisons codegen for this kernel.
//  - (256,4) is proven clean: R0 compiled to 60 VGPR, zero spill. And since
//    launch_bounds is only an allocator hint, runtime residency follows ACTUAL
//    usage: VGPR 60 (-> 64 granule, 8 waves/SIMD) + 12.8 KB LDS (12 blocks/CU)
//    already permits 8 blocks/CU. No forcing needed.
//  - DCHUNK 16: grid = 10x10x20 = 2000 blocks = 8000 waves ~ 98% of the 8192
//    device wave slots, all co-resident.
//  - single-buffered LDS: A(k+1) writes ordered after B(k) reads by sync2(k);
//    B(k+1) writes after C(k) reads by sync1(k+1).
//  - finalize fused into last-finishing block (atomic counter).
// d_ws: [0:8) double accumulator, [8:12) unsigned completion counter.

#define NB   2
#define NDIM 160
#define TILE 16
#define RE   24      // TILE + 8 halo
#define DCHUNK 16
#define NDCHUNK (NDIM / DCHUNK)   // 10
#define NSLICE (DCHUNK + 8)       // 24 real slices per block
#define NBLK ((NDIM/TILE)*(NDIM/TILE)*NB*NDCHUNK)   // 2000

__global__ __launch_bounds__(256, 4)
void ncc_main(const float* __restrict__ I, const float* __restrict__ J,
              double* __restrict__ out_acc, unsigned int* __restrict__ out_cnt,
              float* __restrict__ out) {
    const int t  = threadIdx.x;
    const int tx = t & 15;
    const int ty = t >> 4;
    const int w0 = blockIdx.x * TILE;
    const int h0 = blockIdx.y * TILE;
    const int b  = blockIdx.z / NDCHUNK;
    const int d0 = (blockIdx.z % NDCHUNK) * DCHUNK;

    const float* Ib = I + (size_t)b * NDIM * NDIM * NDIM;
    const float* Jb = J + (size_t)b * NDIM * NDIM * NDIM;

    // Single-buffered LDS (safe with the 2 barriers; see header note).
    __shared__ float2 sIJ[RE][25];       // interleaved I,J halo (col pad)
    __shared__ float4 rsv[RE][TILE];     // row sums: {I, J, I2, J2}
    __shared__ float  rss[RE][TILE];     // row sums: IJ
    __shared__ double wsum[4];

    // D-window ring in REGISTERS: ring[j][c], j indexed by constants only.
    float ring[9][5];
#pragma unroll
    for (int k = 0; k < 9; ++k)
#pragma unroll
        for (int c = 0; c < 5; ++c) ring[k][c] = 0.0f;

    float acc[5] = {0.f, 0.f, 0.f, 0.f, 0.f};
    double csum = 0.0;
    const float inv_win = 1.0f / 729.0f;

    // 27 steps (24 real + 3 dummy so step%9 == j is exact); slice dz = d0-4+step.
    // After folding slice dz, acc = box-sum over slices [dz-8, dz]; output
    // d = dz-4 is emitted for steps 8..23.
    for (int o = 0; o < 3; ++o) {
#pragma unroll
        for (int j = 0; j < 9; ++j) {
            const int step = o * 9 + j;
            const int dz = d0 - 4 + step;
            float s[5] = {0.f, 0.f, 0.f, 0.f, 0.f};
            if (step < NSLICE && (unsigned)dz < NDIM) {   // block-uniform
                // Phase A: stage 24x24 halo (zero-padded) as float2
                for (int e = t; e < RE * RE; e += 256) {
                    int r = e / RE, c2 = e - r * RE;
                    int h = h0 - 4 + r, w = w0 - 4 + c2;
                    float vi = 0.f, vj = 0.f;
                    if ((unsigned)h < NDIM && (unsigned)w < NDIM) {
                        size_t idx = ((size_t)dz * NDIM + h) * NDIM + w;
                        vi = Ib[idx];
                        vj = Jb[idx];
                    }
                    sIJ[r][c2] = make_float2(vi, vj);
                }
                __syncthreads();
                // Phase B: 9-tap row sums along W, 5 channels, 24x16 items
                for (int p = t; p < RE * TILE; p += 256) {
                    int r = p >> 4, wo = p & 15;
                    float a0 = 0.f, a1 = 0.f, a2 = 0.f, a3 = 0.f, a4 = 0.f;
#pragma unroll
                    for (int k = 0; k < 9; ++k) {
                        float2 v = sIJ[r][wo + k];
                        a0 += v.x; a1 += v.y;
                        a2 += v.x * v.x; a3 += v.y * v.y; a4 += v.x * v.y;
                    }
                    rsv[r][wo] = make_float4(a0, a1, a2, a3);
                    rss[r][wo] = a4;
                }
                __syncthreads();
                // Phase C: 9-tap column sums along H at (ty, tx)
                float s0 = 0.f, s1 = 0.f, s2 = 0.f, s3 = 0.f, s4 = 0.f;
#pragma unroll
                for (int k = 0; k < 9; ++k) {
                    float4 v = rsv[ty + k][tx];
                    s0 += v.x; s1 += v.y; s2 += v.z; s3 += v.w;
                    s4 += rss[ty + k][tx];
                }
                s[0] = s0; s[1] = s1; s[2] = s2; s[3] = s3; s[4] = s4;
            }
            // Slide the D-window (constant slot j -> pure registers)
#pragma unroll
            for (int c = 0; c < 5; ++c) {
                acc[c] += s[c] - ring[j][c];
                ring[j][c] = s[c];
            }
            if (step >= 8 && step < 8 + DCHUNK) {
                float Is = acc[0], Js = acc[1];
                float I2 = acc[2], J2 = acc[3], IJ = acc[4];
                float cross = IJ - Is * Js * inv_win;
                float Ivar  = I2 - Is * Is * inv_win;
                float Jvar  = J2 - Js * Js * inv_win;
                float cc = cross * cross / (Ivar * Jvar + 1e-5f);
                csum += (double)cc;
            }
        }
    }

    // Block reduction: wave shuffle, then cross-wave via LDS.
#pragma unroll
    for (int off = 32; off > 0; off >>= 1)
        csum += __shfl_down(csum, off, 64);
    if ((t & 63) == 0) wsum[t >> 6] = csum;
    __syncthreads();
    if (t == 0) {
        double total = wsum[0] + wsum[1] + wsum[2] + wsum[3];
        atomicAdd(out_acc, total);
        __threadfence();
        unsigned int old = atomicAdd(out_cnt, 1u);
        if (old == NBLK - 1) {
            // All other blocks' acc adds are ordered before their counter
            // increments (threadfence); atomic read returns the full total.
            double fin = atomicAdd(out_acc, 0.0);
            out[0] = (float)(-fin / 8192000.0);
        }
    }
}

extern "C" void kernel_launch(void* const* d_in, const int* in_sizes, int n_in,
                              void* d_out, int out_size, void* d_ws, size_t ws_size,
                              hipStream_t stream) {
    const float* I = (const float*)d_in[0];   // y_true
    const float* J = (const float*)d_in[1];   // y_pred
    double* acc = (double*)d_ws;
    unsigned int* cnt = (unsigned int*)((char*)d_ws + 8);

    hipMemsetAsync(d_ws, 0, 16, stream);

    dim3 grid(NDIM / TILE, NDIM / TILE, NB * NDCHUNK);  // 10 x 10 x 20
    ncc_main<<<grid, 256, 0, stream>>>(I, J, acc, cnt, (float*)d_out);
}

// Round 5
// 228.200 us; speedup vs baseline: 1.6816x; 1.0242x over previous
//
#include <hip/hip_runtime.h>

// NCC loss: five 9x9x9 box sums over (2,1,160,160,160) fp32 volumes, fused.
// Separable box filter; block owns a 16x16 (h,w) tile, streams 20 outputs
// along D. D-direction 9-tap window kept in REGISTERS (ring[9][5], slot index
// made compile-time by outer-4 x inner-unrolled-9 loop structure).
//
// R5: drop the __launch_bounds__ waves-per-EU argument entirely.
// Evidence across R0-R4: resident blocks/CU tracked the 2nd launch-bounds
// arg (arg=4 -> ~3-4 blocks both at grid 3.9/CU and 7.8/CU; arg=6 -> 4;
// arg=8 -> 6), NOT the VGPR/LDS resource math (R4: VGPR 64 + 12.8 KB LDS
// permit 8 blocks, grid had 7.8 queued, still ~3 resident, VALUBusy 36%).
// On this toolchain the attribute acts as an occupancy CAP, and >=6 also
// halves the VGPR budget (R1: 32 VGPR + 464 MB spill; R3: 40 + 337 MB).
// With no 2nd arg the allocator's natural ~60 VGPR allocation (proven at
// arg=4) allows 8 waves/SIMD; LDS 12.8 KB allows 12 blocks; HW schedules
// residency freely.
//  - DCHUNK 20: grid = 10x10x16 = 1600 blocks = 6.25/CU queue depth,
//    halo redundancy 28/20 = 1.4 (hedge: R4 showed extra halo work costs
//    real time when occupancy doesn't move).
//  - single-buffered LDS (12.8 KB): A(k+1) writes ordered after B(k) reads
//    by sync2(k); B(k+1) writes after C(k) reads by sync1(k+1).
//  - finalize fused into last-finishing block (atomic counter).
// d_ws: [0:8) double accumulator, [8:12) unsigned completion counter.

#define NB   2
#define NDIM 160
#define TILE 16
#define RE   24      // TILE + 8 halo
#define DCHUNK 20
#define NDCHUNK (NDIM / DCHUNK)   // 8
#define NSLICE (DCHUNK + 8)       // 28 real slices per block
#define NBLK ((NDIM/TILE)*(NDIM/TILE)*NB*NDCHUNK)   // 1600

__global__ __launch_bounds__(256)
void ncc_main(const float* __restrict__ I, const float* __restrict__ J,
              double* __restrict__ out_acc, unsigned int* __restrict__ out_cnt,
              float* __restrict__ out) {
    const int t  = threadIdx.x;
    const int tx = t & 15;
    const int ty = t >> 4;
    const int w0 = blockIdx.x * TILE;
    const int h0 = blockIdx.y * TILE;
    const int b  = blockIdx.z / NDCHUNK;
    const int d0 = (blockIdx.z % NDCHUNK) * DCHUNK;

    const float* Ib = I + (size_t)b * NDIM * NDIM * NDIM;
    const float* Jb = J + (size_t)b * NDIM * NDIM * NDIM;

    // Single-buffered LDS (safe with the 2 barriers; see header note).
    __shared__ float2 sIJ[RE][25];       // interleaved I,J halo (col pad)
    __shared__ float4 rsv[RE][TILE];     // row sums: {I, J, I2, J2}
    __shared__ float  rss[RE][TILE];     // row sums: IJ
    __shared__ double wsum[4];

    // D-window ring in REGISTERS: ring[j][c], j indexed by constants only.
    float ring[9][5];
#pragma unroll
    for (int k = 0; k < 9; ++k)
#pragma unroll
        for (int c = 0; c < 5; ++c) ring[k][c] = 0.0f;

    float acc[5] = {0.f, 0.f, 0.f, 0.f, 0.f};
    double csum = 0.0;
    const float inv_win = 1.0f / 729.0f;

    // 36 steps (28 real + 8 dummy so step%9 == j is exact); slice dz = d0-4+step.
    // After folding slice dz, acc = box-sum over slices [dz-8, dz]; output
    // d = dz-4 is emitted for steps 8..27.
    for (int o = 0; o < 4; ++o) {
#pragma unroll
        for (int j = 0; j < 9; ++j) {
            const int step = o * 9 + j;
            const int dz = d0 - 4 + step;
            float s[5] = {0.f, 0.f, 0.f, 0.f, 0.f};
            if (step < NSLICE && (unsigned)dz < NDIM) {   // block-uniform
                // Phase A: stage 24x24 halo (zero-padded) as float2
                for (int e = t; e < RE * RE; e += 256) {
                    int r = e / RE, c2 = e - r * RE;
                    int h = h0 - 4 + r, w = w0 - 4 + c2;
                    float vi = 0.f, vj = 0.f;
                    if ((unsigned)h < NDIM && (unsigned)w < NDIM) {
                        size_t idx = ((size_t)dz * NDIM + h) * NDIM + w;
                        vi = Ib[idx];
                        vj = Jb[idx];
                    }
                    sIJ[r][c2] = make_float2(vi, vj);
                }
                __syncthreads();
                // Phase B: 9-tap row sums along W, 5 channels, 24x16 items
                for (int p = t; p < RE * TILE; p += 256) {
                    int r = p >> 4, wo = p & 15;
                    float a0 = 0.f, a1 = 0.f, a2 = 0.f, a3 = 0.f, a4 = 0.f;
#pragma unroll
                    for (int k = 0; k < 9; ++k) {
                        float2 v = sIJ[r][wo + k];
                        a0 += v.x; a1 += v.y;
                        a2 += v.x * v.x; a3 += v.y * v.y; a4 += v.x * v.y;
                    }
                    rsv[r][wo] = make_float4(a0, a1, a2, a3);
                    rss[r][wo] = a4;
                }
                __syncthreads();
                // Phase C: 9-tap column sums along H at (ty, tx)
                float s0 = 0.f, s1 = 0.f, s2 = 0.f, s3 = 0.f, s4 = 0.f;
#pragma unroll
                for (int k = 0; k < 9; ++k) {
                    float4 v = rsv[ty + k][tx];
                    s0 += v.x; s1 += v.y; s2 += v.z; s3 += v.w;
                    s4 += rss[ty + k][tx];
                }
                s[0] = s0; s[1] = s1; s[2] = s2; s[3] = s3; s[4] = s4;
            }
            // Slide the D-window (constant slot j -> pure registers)
#pragma unroll
            for (int c = 0; c < 5; ++c) {
                acc[c] += s[c] - ring[j][c];
                ring[j][c] = s[c];
            }
            if (step >= 8 && step < 8 + DCHUNK) {
                float Is = acc[0], Js = acc[1];
                float I2 = acc[2], J2 = acc[3], IJ = acc[4];
                float cross = IJ - Is * Js * inv_win;
                float Ivar  = I2 - Is * Is * inv_win;
                float Jvar  = J2 - Js * Js * inv_win;
                float cc = cross * cross / (Ivar * Jvar + 1e-5f);
                csum += (double)cc;
            }
        }
    }

    // Block reduction: wave shuffle, then cross-wave via LDS.
#pragma unroll
    for (int off = 32; off > 0; off >>= 1)
        csum += __shfl_down(csum, off, 64);
    if ((t & 63) == 0) wsum[t >> 6] = csum;
    __syncthreads();
    if (t == 0) {
        double total = wsum[0] + wsum[1] + wsum[2] + wsum[3];
        atomicAdd(out_acc, total);
        __threadfence();
        unsigned int old = atomicAdd(out_cnt, 1u);
        if (old == NBLK - 1) {
            // All other blocks' acc adds are ordered before their counter
            // increments (threadfence); atomic read returns the full total.
            double fin = atomicAdd(out_acc, 0.0);
            out[0] = (float)(-fin / 8192000.0);
        }
    }
}

extern "C" void kernel_launch(void* const* d_in, const int* in_sizes, int n_in,
                              void* d_out, int out_size, void* d_ws, size_t ws_size,
                              hipStream_t stream) {
    const float* I = (const float*)d_in[0];   // y_true
    const float* J = (const float*)d_in[1];   // y_pred
    double* acc = (double*)d_ws;
    unsigned int* cnt = (unsigned int*)((char*)d_ws + 8);

    hipMemsetAsync(d_ws, 0, 16, stream);

    dim3 grid(NDIM / TILE, NDIM / TILE, NB * NDCHUNK);  // 10 x 10 x 16
    ncc_main<<<grid, 256, 0, stream>>>(I, J, acc, cnt, (float*)d_out);
}

// Round 6
// 191.477 us; speedup vs baseline: 2.0041x; 1.1918x over previous
//
#include <hip/hip_runtime.h>

// NCC loss: five 9x9x9 box sums over (2,1,160,160,160) fp32 volumes, fused.
// Separable box filter; block owns a 32x32 (h,w) tile, streams 16 outputs
// along D. D-window kept in registers (ring[9][5], compile-time slot index).
//
// R6: retile 16x16/256t -> 32x32/1024t. Diagnosis across R0-R5: occupancy
// knobs are exhausted (residency pins near 3 blocks/CU for 4-wave blocks no
// matter the grid/attribute; VALU 35-48%, LDS ~40%, HBM ~15%, conflicts ~1%
// -> barrier-latency-bound). Fixes here:
//  - 4x fewer barriers per output (2 barriers now cover 1024 outputs).
//  - halo work per output: stage 2.25->1.56, row-sums 1.5->1.25.
//  - only 2 blocks/CU needed for 100% wave occupancy (16 waves/block);
//    grid 5x5x20 = 500 blocks ~= 512 device block slots (98% packing).
//  - conflict-free LDS: split sI/sJ with odd (41) row stride; channel-split
//    row-sum arrays rs[5][40][33] so phase C does b32 reads, lane->bank 1:1.
//  - VGPR must stay <=64 for 2-block residency (R5 measured exactly 64 for
//    this body at 256t). No launch_bounds 2nd arg (R1/R3: arg>=6 halves the
//    allocation and spills; arg present at all never helped).
// d_ws: [0:8) double accumulator, [8:12) unsigned completion counter.

#define NB   2
#define NDIM 160
#define TILE 32
#define RE   40      // TILE + 8 halo
#define DCHUNK 16
#define NDCHUNK (NDIM / DCHUNK)   // 10
#define NSLICE (DCHUNK + 8)       // 24 real slices per block
#define NBLK ((NDIM/TILE)*(NDIM/TILE)*NB*NDCHUNK)   // 500
#define NTHR 1024

__global__ __launch_bounds__(NTHR)
void ncc_main(const float* __restrict__ I, const float* __restrict__ J,
              double* __restrict__ out_acc, unsigned int* __restrict__ out_cnt,
              float* __restrict__ out) {
    const int t  = threadIdx.x;
    const int tx = t & 31;
    const int ty = t >> 5;
    const int w0 = blockIdx.x * TILE;
    const int h0 = blockIdx.y * TILE;
    const int b  = blockIdx.z / NDCHUNK;
    const int d0 = (blockIdx.z % NDCHUNK) * DCHUNK;

    const float* Ib = I + (size_t)b * NDIM * NDIM * NDIM;
    const float* Jb = J + (size_t)b * NDIM * NDIM * NDIM;

    // Single-buffered LDS (A(k+1) writes ordered after B(k) reads by sync2(k);
    // B(k+1) writes after C(k) reads by sync1(k+1)).
    __shared__ float sI[RE][RE + 1];          // 41-float row stride (odd)
    __shared__ float sJ[RE][RE + 1];
    __shared__ float rs[5][RE][TILE + 1];     // channel-split row sums
    __shared__ double wsum[NTHR / 64];

    // D-window ring in REGISTERS: ring[j][c], j indexed by constants only.
    float ring[9][5];
#pragma unroll
    for (int k = 0; k < 9; ++k)
#pragma unroll
        for (int c = 0; c < 5; ++c) ring[k][c] = 0.0f;

    float acc[5] = {0.f, 0.f, 0.f, 0.f, 0.f};
    double csum = 0.0;
    const float inv_win = 1.0f / 729.0f;

    // 27 steps (24 real + 3 dummy so step%9 == j is exact); slice dz = d0-4+step.
    // acc = box-sum over slices [dz-8, dz]; output d = dz-4 for steps 8..23.
    for (int o = 0; o < 3; ++o) {
#pragma unroll
        for (int j = 0; j < 9; ++j) {
            const int step = o * 9 + j;
            const int dz = d0 - 4 + step;
            float s[5] = {0.f, 0.f, 0.f, 0.f, 0.f};
            if (step < NSLICE && (unsigned)dz < NDIM) {   // block-uniform
                const float* Izs = Ib + (size_t)dz * NDIM * NDIM;
                const float* Jzs = Jb + (size_t)dz * NDIM * NDIM;
                // Phase A: stage 40x40 halo (zero-padded), split I/J arrays
                for (int e = t; e < RE * RE; e += NTHR) {
                    int r = e / RE, c2 = e - r * RE;
                    int h = h0 - 4 + r, w = w0 - 4 + c2;
                    float vi = 0.f, vj = 0.f;
                    if ((unsigned)h < NDIM && (unsigned)w < NDIM) {
                        int idx = h * NDIM + w;
                        vi = Izs[idx];
                        vj = Jzs[idx];
                    }
                    sI[r][c2] = vi;
                    sJ[r][c2] = vj;
                }
                __syncthreads();
                // Phase B: 9-tap row sums along W, 5 channels, 40x32 items
                for (int p = t; p < RE * TILE; p += NTHR) {
                    int r = p >> 5, wo = p & 31;
                    float a0 = 0.f, a1 = 0.f, a2 = 0.f, a3 = 0.f, a4 = 0.f;
#pragma unroll
                    for (int k = 0; k < 9; ++k) {
                        float vi = sI[r][wo + k];
                        float vj = sJ[r][wo + k];
                        a0 += vi; a1 += vj;
                        a2 += vi * vi; a3 += vj * vj; a4 += vi * vj;
                    }
                    rs[0][r][wo] = a0;
                    rs[1][r][wo] = a1;
                    rs[2][r][wo] = a2;
                    rs[3][r][wo] = a3;
                    rs[4][r][wo] = a4;
                }
                __syncthreads();
                // Phase C: 9-tap column sums along H at (ty, tx); b32 reads,
                // lane tx -> bank tx (conflict-free).
                float s0 = 0.f, s1 = 0.f, s2 = 0.f, s3 = 0.f, s4 = 0.f;
#pragma unroll
                for (int k = 0; k < 9; ++k) {
                    s0 += rs[0][ty + k][tx];
                    s1 += rs[1][ty + k][tx];
                    s2 += rs[2][ty + k][tx];
                    s3 += rs[3][ty + k][tx];
                    s4 += rs[4][ty + k][tx];
                }
                s[0] = s0; s[1] = s1; s[2] = s2; s[3] = s3; s[4] = s4;
            }
            // Slide the D-window (constant slot j -> pure registers)
#pragma unroll
            for (int c = 0; c < 5; ++c) {
                acc[c] += s[c] - ring[j][c];
                ring[j][c] = s[c];
            }
            if (step >= 8 && step < 8 + DCHUNK) {
                float Is = acc[0], Js = acc[1];
                float I2 = acc[2], J2 = acc[3], IJ = acc[4];
                float cross = IJ - Is * Js * inv_win;
                float Ivar  = I2 - Is * Is * inv_win;
                float Jvar  = J2 - Js * Js * inv_win;
                float cc = cross * cross / (Ivar * Jvar + 1e-5f);
                csum += (double)cc;
            }
        }
    }

    // Block reduction: wave shuffle, then cross-wave via LDS (16 waves).
#pragma unroll
    for (int off = 32; off > 0; off >>= 1)
        csum += __shfl_down(csum, off, 64);
    if ((t & 63) == 0) wsum[t >> 6] = csum;
    __syncthreads();
    if (t == 0) {
        double total = 0.0;
#pragma unroll
        for (int wv = 0; wv < NTHR / 64; ++wv) total += wsum[wv];
        atomicAdd(out_acc, total);
        __threadfence();
        unsigned int old = atomicAdd(out_cnt, 1u);
        if (old == NBLK - 1) {
            // All other blocks' acc adds are ordered before their counter
            // increments (threadfence); atomic read returns the full total.
            double fin = atomicAdd(out_acc, 0.0);
            out[0] = (float)(-fin / 8192000.0);
        }
    }
}

extern "C" void kernel_launch(void* const* d_in, const int* in_sizes, int n_in,
                              void* d_out, int out_size, void* d_ws, size_t ws_size,
                              hipStream_t stream) {
    const float* I = (const float*)d_in[0];   // y_true
    const float* J = (const float*)d_in[1];   // y_pred
    double* acc = (double*)d_ws;
    unsigned int* cnt = (unsigned int*)((char*)d_ws + 8);

    hipMemsetAsync(d_ws, 0, 16, stream);

    dim3 grid(NDIM / TILE, NDIM / TILE, NB * NDCHUNK);  // 5 x 5 x 20
    ncc_main<<<grid, NTHR, 0, stream>>>(I, J, acc, cnt, (float*)d_out);
}

// Round 7
// 146.438 us; speedup vs baseline: 2.6205x; 1.3076x over previous
//
#include <hip/hip_runtime.h>

// NCC loss: five 9x9x9 box sums over (2,1,160,160,160) fp32 volumes, fused.
// Separable box filter; block owns a 32x32 (h,w) tile, streams 32 outputs
// along D. D-window in registers (ring[9][5], compile-time slot index).
//
// R7: restore the software pipeline R0 had (and R1 removed), on the R6
// big-tile structure. Post-mortem R6: VALUBusy 46% of 128us ~= the ~55us
// VALU floor of this algorithm; the other ~half is stall because single-
// buffered staging puts global-load latency + LDS writes serially inside
// the barrier critical path (compiler can't hoist loads across barriers).
//  - double-buffered sI/sJ + async-stage split (T14): next-slice global
//    loads issued to REGS at top of step, written to the other buffer
//    after phase B; latency hides under row-sum compute.
//  - DCHUNK 32: slice redundancy 40/32=1.25 (was 1.5); grid 5x5x10 = 250
//    blocks <= 256 CUs -> exactly 1 block/CU, uniform makespan, no
//    dependence on the (never-responsive) multi-block residency.
//  - row sums packed float4+float (R0 layout): phase C 9 b128 + 9 b32
//    instead of 45 b32 (same bank-cycles, 2.5x fewer issue slots).
//  - occupancy knobs abandoned: R1-R6 showed residency*VGPR ~= const and
//    launch_bounds 2nd arg >=6 spills (VGPR halved, WRITE_SIZE 300+MB).
// d_ws: [0:8) double accumulator, [8:12) unsigned completion counter.

#define NB   2
#define NDIM 160
#define TILE 32
#define RE   40      // TILE + 8 halo
#define DCHUNK 32
#define NDCHUNK (NDIM / DCHUNK)   // 5
#define NSLICE (DCHUNK + 8)       // 40 real slices per block
#define NBLK ((NDIM/TILE)*(NDIM/TILE)*NB*NDCHUNK)   // 250
#define NTHR 1024
#define SLICE_SZ (NDIM * NDIM)

__global__ __launch_bounds__(NTHR)
void ncc_main(const float* __restrict__ I, const float* __restrict__ J,
              double* __restrict__ out_acc, unsigned int* __restrict__ out_cnt,
              float* __restrict__ out) {
    const int t  = threadIdx.x;
    const int tx = t & 31;
    const int ty = t >> 5;
    const int w0 = blockIdx.x * TILE;
    const int h0 = blockIdx.y * TILE;
    const int b  = blockIdx.z / NDCHUNK;
    const int d0 = (blockIdx.z % NDCHUNK) * DCHUNK;

    const float* Ib = I + (size_t)b * NDIM * SLICE_SZ;
    const float* Jb = J + (size_t)b * NDIM * SLICE_SZ;

    // Double-buffered halo slices; row sums single-buffered (protected by
    // the two barriers: B->C by barrier1, C->next-B by barrier2).
    __shared__ float  sI[2][RE][RE + 1];      // 41-float row stride (odd)
    __shared__ float  sJ[2][RE][RE + 1];
    __shared__ float4 rs4[RE][TILE + 1];      // row sums {I, J, I2, J2}
    __shared__ float  rss[RE][TILE + 1];      // row sums IJ
    __shared__ double wsum[NTHR / 64];

    // Per-thread halo staging coords (1600 items / 1024 threads -> 2 slots,
    // slot1 active for t < 576). Precomputed once; reused every slice.
    const int e1 = t + NTHR;
    const int r0 = t / RE,  c0 = t - r0 * RE;
    const int r1 = e1 / RE, c1 = e1 - r1 * RE;
    const int h_0 = h0 - 4 + r0, w_0 = w0 - 4 + c0;
    const int h_1 = h0 - 4 + r1, w_1 = w0 - 4 + c1;
    const bool has1 = (e1 < RE * RE);
    const bool in0 = ((unsigned)h_0 < NDIM) && ((unsigned)w_0 < NDIM);
    const bool in1 = has1 && ((unsigned)h_1 < NDIM) && ((unsigned)w_1 < NDIM);
    const int idx0 = h_0 * NDIM + w_0;
    const int idx1 = h_1 * NDIM + w_1;

    // D-window ring in REGISTERS: ring[j][c], j indexed by constants only.
    float ring[9][5];
#pragma unroll
    for (int k = 0; k < 9; ++k)
#pragma unroll
        for (int c = 0; c < 5; ++c) ring[k][c] = 0.0f;

    float acc[5] = {0.f, 0.f, 0.f, 0.f, 0.f};
    double csum = 0.0;
    const float inv_win = 1.0f / 729.0f;
    int cur = 0;

    // Prologue: stage slice for step 0 (dz = d0-4) if valid.
    {
        const int dz0 = d0 - 4;
        if ((unsigned)dz0 < NDIM) {
            const float* Iz = Ib + (size_t)dz0 * SLICE_SZ;
            const float* Jz = Jb + (size_t)dz0 * SLICE_SZ;
            float vi0 = in0 ? Iz[idx0] : 0.f;
            float vj0 = in0 ? Jz[idx0] : 0.f;
            sI[0][r0][c0] = vi0;
            sJ[0][r0][c0] = vj0;
            if (has1) {
                float vi1 = in1 ? Iz[idx1] : 0.f;
                float vj1 = in1 ? Jz[idx1] : 0.f;
                sI[0][r1][c1] = vi1;
                sJ[0][r1][c1] = vj1;
            }
        }
        __syncthreads();
    }

    // 45 steps (40 real + 5 dummy so step%9 == j exactly); slice dz = d0-4+step.
    // acc = box-sum over slices [dz-8, dz]; output d = dz-4 for steps 8..39.
    for (int o = 0; o < 5; ++o) {
#pragma unroll
        for (int j = 0; j < 9; ++j) {
            const int step = o * 9 + j;
            const int dz = d0 - 4 + step;
            float s[5] = {0.f, 0.f, 0.f, 0.f, 0.f};
            if (step < NSLICE) {                       // block-uniform
                // Prefetch next slice to REGISTERS (issued before compute;
                // HBM/L2 latency hides under phase B).
                const int dzn = dz + 1;
                const bool pf = (step + 1 < NSLICE) && ((unsigned)dzn < NDIM);
                float pvi0 = 0.f, pvj0 = 0.f, pvi1 = 0.f, pvj1 = 0.f;
                if (pf) {
                    const float* Iz = Ib + (size_t)dzn * SLICE_SZ;
                    const float* Jz = Jb + (size_t)dzn * SLICE_SZ;
                    if (in0) { pvi0 = Iz[idx0]; pvj0 = Jz[idx0]; }
                    if (in1) { pvi1 = Iz[idx1]; pvj1 = Jz[idx1]; }
                }
                if ((unsigned)dz < NDIM) {             // block-uniform
                    // Phase B: 9-tap row sums along W, 5 channels, 40x32 items
                    for (int p = t; p < RE * TILE; p += NTHR) {
                        int r = p >> 5, wo = p & 31;
                        float a0 = 0.f, a1 = 0.f, a2 = 0.f, a3 = 0.f, a4 = 0.f;
#pragma unroll
                        for (int k = 0; k < 9; ++k) {
                            float vi = sI[cur][r][wo + k];
                            float vj = sJ[cur][r][wo + k];
                            a0 += vi; a1 += vj;
                            a2 += vi * vi; a3 += vj * vj; a4 += vi * vj;
                        }
                        rs4[r][wo] = make_float4(a0, a1, a2, a3);
                        rss[r][wo] = a4;
                    }
                }
                // Stage prefetched slice into the OTHER buffer. Its previous
                // readers (phase B of step-1) finished before the last
                // barrier; next readers come after the barrier below.
                if (pf) {
                    const int nxt = cur ^ 1;
                    sI[nxt][r0][c0] = pvi0;
                    sJ[nxt][r0][c0] = pvj0;
                    if (has1) {
                        sI[nxt][r1][c1] = pvi1;
                        sJ[nxt][r1][c1] = pvj1;
                    }
                }
                __syncthreads();                        // rs ready; stage done
                if ((unsigned)dz < NDIM) {
                    // Phase C: 9-tap column sums along H at (ty, tx)
                    float s0 = 0.f, s1 = 0.f, s2 = 0.f, s3 = 0.f, s4 = 0.f;
#pragma unroll
                    for (int k = 0; k < 9; ++k) {
                        float4 v = rs4[ty + k][tx];
                        s0 += v.x; s1 += v.y; s2 += v.z; s3 += v.w;
                        s4 += rss[ty + k][tx];
                    }
                    s[0] = s0; s[1] = s1; s[2] = s2; s[3] = s3; s[4] = s4;
                }
                __syncthreads();                        // rs free for next B
                cur ^= 1;
            }
            // Slide the D-window (constant slot j -> pure registers)
#pragma unroll
            for (int c = 0; c < 5; ++c) {
                acc[c] += s[c] - ring[j][c];
                ring[j][c] = s[c];
            }
            if (step >= 8 && step < 8 + DCHUNK) {
                float Is = acc[0], Js = acc[1];
                float I2 = acc[2], J2 = acc[3], IJ = acc[4];
                float cross = IJ - Is * Js * inv_win;
                float Ivar  = I2 - Is * Is * inv_win;
                float Jvar  = J2 - Js * Js * inv_win;
                float cc = cross * cross / (Ivar * Jvar + 1e-5f);
                csum += (double)cc;
            }
        }
    }

    // Block reduction: wave shuffle, then cross-wave via LDS (16 waves).
#pragma unroll
    for (int off = 32; off > 0; off >>= 1)
        csum += __shfl_down(csum, off, 64);
    if ((t & 63) == 0) wsum[t >> 6] = csum;
    __syncthreads();
    if (t == 0) {
        double total = 0.0;
#pragma unroll
        for (int wv = 0; wv < NTHR / 64; ++wv) total += wsum[wv];
        atomicAdd(out_acc, total);
        __threadfence();
        unsigned int old = atomicAdd(out_cnt, 1u);
        if (old == NBLK - 1) {
            // All other blocks' acc adds are ordered before their counter
            // increments (threadfence); atomic read returns the full total.
            double fin = atomicAdd(out_acc, 0.0);
            out[0] = (float)(-fin / 8192000.0);
        }
    }
}

extern "C" void kernel_launch(void* const* d_in, const int* in_sizes, int n_in,
                              void* d_out, int out_size, void* d_ws, size_t ws_size,
                              hipStream_t stream) {
    const float* I = (const float*)d_in[0];   // y_true
    const float* J = (const float*)d_in[1];   // y_pred
    double* acc = (double*)d_ws;
    unsigned int* cnt = (unsigned int*)((char*)d_ws + 8);

    hipMemsetAsync(d_ws, 0, 16, stream);

    dim3 grid(NDIM / TILE, NDIM / TILE, NB * NDCHUNK);  // 5 x 5 x 10
    ncc_main<<<grid, NTHR, 0, stream>>>(I, J, acc, cnt, (float*)d_out);
}